// Round 1
// baseline (840.411 us; speedup 1.0000x reference)
//
#include <hip/hip_runtime.h>
#include <hip/hip_bf16.h>
#include <stdint.h>

#define NTOK 49
#define CDIM 192
#define NHEADS 6

typedef __attribute__((ext_vector_type(8))) short bf16x8;
typedef __attribute__((ext_vector_type(4))) float f32x4;

// RNE float -> bf16 (bit trick)
__device__ __forceinline__ short f2b(float f) {
    uint32_t u = __float_as_uint(f);
    uint32_t r = (u + 0x7fffu + ((u >> 16) & 1u)) >> 16;
    return (short)r;
}

// Fast pack: 8 consecutive fp32 -> bf16x8 (round-half-up via +0x8000, then v_perm)
__device__ __forceinline__ bf16x8 cvt8(const float* p) {
    f32x4 a = *(const f32x4*)p;
    f32x4 b = *(const f32x4*)(p + 4);
    union { uint32_t u[4]; bf16x8 v; } r;
    uint32_t e0 = __float_as_uint(a[0]) + 0x8000u, e1 = __float_as_uint(a[1]) + 0x8000u;
    uint32_t e2 = __float_as_uint(a[2]) + 0x8000u, e3 = __float_as_uint(a[3]) + 0x8000u;
    uint32_t e4 = __float_as_uint(b[0]) + 0x8000u, e5 = __float_as_uint(b[1]) + 0x8000u;
    uint32_t e6 = __float_as_uint(b[2]) + 0x8000u, e7 = __float_as_uint(b[3]) + 0x8000u;
    r.u[0] = __builtin_amdgcn_perm(e1, e0, 0x07060302u);
    r.u[1] = __builtin_amdgcn_perm(e3, e2, 0x07060302u);
    r.u[2] = __builtin_amdgcn_perm(e5, e4, 0x07060302u);
    r.u[3] = __builtin_amdgcn_perm(e7, e6, 0x07060302u);
    return r.v;
}

// One-shot: transpose+cast qkv_w [192][576]f32 -> wt [576][192]bf16,
//           proj_w [192][192]f32 -> pwt [192][192]bf16
__global__ void transpose_w(const float* __restrict__ qkv_w,
                            const float* __restrict__ proj_w,
                            short* __restrict__ wt, short* __restrict__ pwt) {
    int idx = blockIdx.x * 256 + threadIdx.x;
    if (idx < CDIM * 3 * CDIM) {
        int c = idx / (3 * CDIM), j = idx % (3 * CDIM);
        wt[j * CDIM + c] = f2b(qkv_w[idx]);
    }
    if (idx < CDIM * CDIM) {
        int c = idx / CDIM, j = idx % CDIM;
        pwt[j * CDIM + c] = f2b(proj_w[idx]);
    }
}

// ===================== new split path =====================
// Kernel 1: one block per (window, head). 4 waves; wave wv owns token mtile wv.
// Single __syncthreads per block; attention phase is fully wave-private.
__global__ __launch_bounds__(256, 4)
void attn_head_kernel(const float* __restrict__ x, const float* __restrict__ mask,
                      const short* __restrict__ wt, const float* __restrict__ qkvb,
                      short* __restrict__ obuf /* [B][64][CDIM] bf16 */) {
    // 29.2 KB LDS -> LDS allows 5 blocks/CU; VGPR cap (256,4) -> 4 blocks/CU.
    __shared__ __align__(16) short qbuf[64][40];    // [token][d]  d<32
    __shared__ __align__(16) short kbuf[64][40];    // [token][d]
    __shared__ __align__(16) short vtbuf[32][72];   // [d][token] (V transposed)
    __shared__ __align__(16) short Pbuf[4][16][72]; // per-wave P rows (A-layout)
    __shared__ __align__(16) short OSbuf[4][16][40];// per-wave O staging

    const int bid = blockIdx.x;
    const int b = bid / NHEADS;
    const int h = bid - b * NHEADS;
    const int tid = threadIdx.x;
    const int wv = tid >> 6;
    const int lane = tid & 63;
    const int q4 = lane >> 4;
    const int l16 = lane & 15;

    // ---- x A-frags: own mtile only (6 frags) ----
    const float* xg = x + (size_t)b * NTOK * CDIM;
    bf16x8 zero = {};
    const int n = wv * 16 + l16;
    const bool valid = (n < NTOK);
    const float* xr = xg + n * CDIM;
    bf16x8 afr[6];
#pragma unroll
    for (int ks = 0; ks < 6; ks++)
        afr[ks] = valid ? cvt8(xr + ks * 32 + q4 * 8) : zero;

    // ---- premask (independent loads, issued early to hide latency) ----
    const float* mg = mask + (size_t)(b & 63) * NTOK * NTOK;
    float premask[4][4];
#pragma unroll
    for (int ct = 0; ct < 4; ct++)
#pragma unroll
        for (int r = 0; r < 4; r++) {
            int row = wv * 16 + q4 * 4 + r;
            int col = ct * 16 + l16;
            float mv = mg[min(row, 48) * NTOK + min(col, 48)];
            premask[ct][r] = (row < NTOK && col < NTOK) ? mv : -1e30f;
        }

    // ---- QKV for this head: 6 jtiles = [q0 q1 k0 k1 v0 v1] ----
#pragma unroll
    for (int jt = 0; jt < 6; jt++) {
        int sect = jt >> 1;                            // 0=q 1=k 2=v
        int jb = sect * CDIM + h * 32 + (jt & 1) * 16; // col in [0,576)
        const short* wrow = wt + (size_t)(jb + l16) * CDIM;
        bf16x8 bfr[6];
#pragma unroll
        for (int ks = 0; ks < 6; ks++)
            bfr[ks] = *(const bf16x8*)(wrow + ks * 32 + q4 * 8);
        f32x4 acc = (f32x4){0.f, 0.f, 0.f, 0.f};
#pragma unroll
        for (int ks = 0; ks < 6; ks++)
            acc = __builtin_amdgcn_mfma_f32_16x16x32_bf16(afr[ks], bfr[ks], acc, 0, 0, 0);
        float bias = qkvb[jb + l16];
        int d = (jt & 1) * 16 + l16;
#pragma unroll
        for (int r = 0; r < 4; r++) {
            int row = wv * 16 + q4 * 4 + r;
            short v = f2b(acc[r] + bias);
            if (sect == 0)      qbuf[row][d] = v;
            else if (sect == 1) kbuf[row][d] = v;
            else                vtbuf[d][row] = v;
        }
    }
    __syncthreads();   // the only barrier: K/V rows from all waves

    const float SCALE = 0.17677669529663687f;

    // ---- S = Q K^T (wave's 16 query rows; K=32 in one MFMA) ----
    f32x4 accs[4];
#pragma unroll
    for (int c = 0; c < 4; c++) accs[c] = (f32x4){0.f, 0.f, 0.f, 0.f};
    bf16x8 qa = *(const bf16x8*)&qbuf[wv * 16 + l16][q4 * 8];
#pragma unroll
    for (int ct = 0; ct < 4; ct++) {
        bf16x8 kb = *(const bf16x8*)&kbuf[ct * 16 + l16][q4 * 8];
        accs[ct] = __builtin_amdgcn_mfma_f32_16x16x32_bf16(qa, kb, accs[ct], 0, 0, 0);
    }

    // ---- softmax across 64 cols: in-lane over 4 ct + 16-lane xor shuffle ----
    float s[4][4], mx[4], lsum[4];
#pragma unroll
    for (int r = 0; r < 4; r++) {
        mx[r] = -3.4e38f;
#pragma unroll
        for (int ct = 0; ct < 4; ct++) {
            s[ct][r] = accs[ct][r] * SCALE + premask[ct][r];
            mx[r] = fmaxf(mx[r], s[ct][r]);
        }
    }
#pragma unroll
    for (int w2 = 1; w2 < 16; w2 <<= 1)
#pragma unroll
        for (int r = 0; r < 4; r++) mx[r] = fmaxf(mx[r], __shfl_xor(mx[r], w2));
#pragma unroll
    for (int r = 0; r < 4; r++) lsum[r] = 0.f;
#pragma unroll
    for (int ct = 0; ct < 4; ct++)
#pragma unroll
        for (int r = 0; r < 4; r++) {
            float e = __expf(s[ct][r] - mx[r]);
            s[ct][r] = e;
            lsum[r] += e;
        }
#pragma unroll
    for (int w2 = 1; w2 < 16; w2 <<= 1)
#pragma unroll
        for (int r = 0; r < 4; r++) lsum[r] += __shfl_xor(lsum[r], w2);

    // ---- P -> per-wave LDS (C-layout -> A-layout), unnormalized ----
#pragma unroll
    for (int ct = 0; ct < 4; ct++)
#pragma unroll
        for (int r = 0; r < 4; r++)
            Pbuf[wv][q4 * 4 + r][ct * 16 + l16] = f2b(s[ct][r]);

    // ---- O = P V (wave-private; no barrier needed) ----
    f32x4 accp[2];
    accp[0] = (f32x4){0.f, 0.f, 0.f, 0.f};
    accp[1] = (f32x4){0.f, 0.f, 0.f, 0.f};
#pragma unroll
    for (int ks = 0; ks < 2; ks++) {
        bf16x8 pa = *(const bf16x8*)&Pbuf[wv][l16][ks * 32 + q4 * 8];
#pragma unroll
        for (int jt = 0; jt < 2; jt++) {
            bf16x8 vb = *(const bf16x8*)&vtbuf[jt * 16 + l16][ks * 32 + q4 * 8];
            accp[jt] = __builtin_amdgcn_mfma_f32_16x16x32_bf16(pa, vb, accp[jt], 0, 0, 0);
        }
    }
    float rl[4];
#pragma unroll
    for (int r = 0; r < 4; r++) rl[r] = 1.0f / lsum[r];

    // ---- normalize, stage in wave-private LDS, coalesced bf16 store ----
#pragma unroll
    for (int jt = 0; jt < 2; jt++)
#pragma unroll
        for (int r = 0; r < 4; r++)
            OSbuf[wv][q4 * 4 + r][jt * 16 + l16] = f2b(accp[jt][r] * rl[r]);
    bf16x8 ox = *(const bf16x8*)&OSbuf[wv][l16][q4 * 8];
    short* op = obuf + ((size_t)(b * 64 + wv * 16 + l16)) * CDIM + h * 32 + q4 * 8;
    *(bf16x8*)op = ox;
}

// Kernel 2: proj GEMM [B*64,192] x [192,192] + bias -> fp32 out (valid rows only).
// No LDS, no barriers; wave wv owns 3 col-tiles, mtiles processed in pairs.
__global__ __launch_bounds__(256, 4)
void proj_kernel(const short* __restrict__ obuf, const short* __restrict__ pwt,
                 const float* __restrict__ projb, float* __restrict__ out) {
    const int b = blockIdx.x;
    const int tid = threadIdx.x;
    const int wv = tid >> 6;
    const int lane = tid & 63;
    const int q4 = lane >> 4;
    const int l16 = lane & 15;
    const short* og = obuf + (size_t)b * 64 * CDIM;

#pragma unroll
    for (int mp = 0; mp < 2; mp++) {
        bf16x8 afr[2][6];
#pragma unroll
        for (int mt = 0; mt < 2; mt++) {
            int row = mp * 32 + mt * 16 + l16;
#pragma unroll
            for (int ks = 0; ks < 6; ks++)
                afr[mt][ks] = *(const bf16x8*)(og + (size_t)row * CDIM + ks * 32 + q4 * 8);
        }
#pragma unroll
        for (int jtl = 0; jtl < 3; jtl++) {
            int jb = (wv * 3 + jtl) * 16;
            const short* wrow = pwt + (size_t)(jb + l16) * CDIM;
            bf16x8 bfr[6];
#pragma unroll
            for (int ks = 0; ks < 6; ks++)
                bfr[ks] = *(const bf16x8*)(wrow + ks * 32 + q4 * 8);
            float bias = projb[jb + l16];
#pragma unroll
            for (int mt = 0; mt < 2; mt++) {
                f32x4 acc = (f32x4){0.f, 0.f, 0.f, 0.f};
#pragma unroll
                for (int ks = 0; ks < 6; ks++)
                    acc = __builtin_amdgcn_mfma_f32_16x16x32_bf16(afr[mt][ks], bfr[ks], acc, 0, 0, 0);
#pragma unroll
                for (int r = 0; r < 4; r++) {
                    int nrow = mp * 32 + mt * 16 + q4 * 4 + r;
                    if (nrow < NTOK)
                        out[((size_t)b * NTOK + nrow) * CDIM + jb + l16] = acc[r] + bias;
                }
            }
        }
    }
}

// ===================== fallback fused path (previous best, verified) =====================
__global__ __launch_bounds__(256, 1)
void winattn_kernel(const float* __restrict__ x, const float* __restrict__ mask,
                    const short* __restrict__ wt, const float* __restrict__ qkvb,
                    const short* __restrict__ pwt, const float* __restrict__ projb,
                    float* __restrict__ out) {
    __shared__ __align__(16) short qbuf[2][64][40];
    __shared__ __align__(16) short kbuf[2][64][40];
    __shared__ __align__(16) short vtbuf[2][32][72];
    __shared__ __align__(16) short Pbuf[4][16][72];
    __shared__ __align__(16) short Obuf[64][40];

    const int b = blockIdx.x;
    const int tid = threadIdx.x;
    const int wv = tid >> 6;
    const int lane = tid & 63;
    const int q4 = lane >> 4;
    const int l16 = lane & 15;

    const float* xg = x + (size_t)b * NTOK * CDIM;
    bf16x8 zero = {};
    bf16x8 afr[4][6];
#pragma unroll
    for (int mt = 0; mt < 4; mt++) {
        int n = mt * 16 + l16;
        const float* xr = xg + n * CDIM;
        bool valid = (n < NTOK);
#pragma unroll
        for (int ks = 0; ks < 6; ks++)
            afr[mt][ks] = valid ? cvt8(xr + ks * 32 + q4 * 8) : zero;
    }

    const float* mg = mask + (size_t)(b & 63) * NTOK * NTOK;
    float premask[4][4];
#pragma unroll
    for (int ct = 0; ct < 4; ct++)
#pragma unroll
        for (int r = 0; r < 4; r++) {
            int row = wv * 16 + q4 * 4 + r;
            int col = ct * 16 + l16;
            float mv = mg[min(row, 48) * NTOK + min(col, 48)];
            premask[ct][r] = (row < NTOK && col < NTOK) ? mv : -1e30f;
        }

    f32x4 acco[3][4];
#pragma unroll
    for (int a = 0; a < 3; a++)
#pragma unroll
        for (int m = 0; m < 4; m++) acco[a][m] = (f32x4){0.f, 0.f, 0.f, 0.f};

    const float SCALE = 0.17677669529663687f;

    for (int p = 0; p < 3; p++) {
        __syncthreads();
#pragma unroll
        for (int t = 0; t < 3; t++) {
            int i = wv * 3 + t;
            int jt;
            if (i < 4)      jt = 4 * p + i;
            else if (i < 8) jt = 12 + 4 * p + (i - 4);
            else            jt = 24 + 4 * p + (i - 8);
            int jb = jt * 16;
            const short* wrow = wt + (size_t)(jb + l16) * CDIM;
            bf16x8 bfr[6];
#pragma unroll
            for (int ks = 0; ks < 6; ks++)
                bfr[ks] = *(const bf16x8*)(wrow + ks * 32 + q4 * 8);
            f32x4 acc[4];
#pragma unroll
            for (int m = 0; m < 4; m++) acc[m] = (f32x4){0.f, 0.f, 0.f, 0.f};
#pragma unroll
            for (int ks = 0; ks < 6; ks++)
#pragma unroll
                for (int mt = 0; mt < 4; mt++)
                    acc[mt] = __builtin_amdgcn_mfma_f32_16x16x32_bf16(afr[mt][ks], bfr[ks], acc[mt], 0, 0, 0);
            float bias = qkvb[jb + l16];
            int sect = jb / CDIM;
            int jm = jb % CDIM;
            int hl = (jm / 32) - 2 * p;
            int d = (jm % 32) + l16;
#pragma unroll
            for (int mt = 0; mt < 4; mt++)
#pragma unroll
                for (int r = 0; r < 4; r++) {
                    int row = mt * 16 + q4 * 4 + r;
                    short v = f2b(acc[mt][r] + bias);
                    if (sect == 0)      qbuf[hl][row][d] = v;
                    else if (sect == 1) kbuf[hl][row][d] = v;
                    else                vtbuf[hl][d][row] = v;
                }
        }
        __syncthreads();

#pragma unroll
        for (int hl = 0; hl < 2; hl++) {
            int h = 2 * p + hl;
            f32x4 accs[4];
#pragma unroll
            for (int c = 0; c < 4; c++) accs[c] = (f32x4){0.f, 0.f, 0.f, 0.f};
            bf16x8 qa = *(const bf16x8*)&qbuf[hl][wv * 16 + l16][q4 * 8];
#pragma unroll
            for (int ct = 0; ct < 4; ct++) {
                bf16x8 kb = *(const bf16x8*)&kbuf[hl][ct * 16 + l16][q4 * 8];
                accs[ct] = __builtin_amdgcn_mfma_f32_16x16x32_bf16(qa, kb, accs[ct], 0, 0, 0);
            }
            float s[4][4], mx[4], lsum[4];
#pragma unroll
            for (int r = 0; r < 4; r++) {
                mx[r] = -3.4e38f;
#pragma unroll
                for (int ct = 0; ct < 4; ct++) {
                    s[ct][r] = accs[ct][r] * SCALE + premask[ct][r];
                    mx[r] = fmaxf(mx[r], s[ct][r]);
                }
            }
#pragma unroll
            for (int w2 = 1; w2 < 16; w2 <<= 1)
#pragma unroll
                for (int r = 0; r < 4; r++) mx[r] = fmaxf(mx[r], __shfl_xor(mx[r], w2));
#pragma unroll
            for (int r = 0; r < 4; r++) lsum[r] = 0.f;
#pragma unroll
            for (int ct = 0; ct < 4; ct++)
#pragma unroll
                for (int r = 0; r < 4; r++) {
                    float e = __expf(s[ct][r] - mx[r]);
                    s[ct][r] = e;
                    lsum[r] += e;
                }
#pragma unroll
            for (int w2 = 1; w2 < 16; w2 <<= 1)
#pragma unroll
                for (int r = 0; r < 4; r++) lsum[r] += __shfl_xor(lsum[r], w2);
#pragma unroll
            for (int ct = 0; ct < 4; ct++)
#pragma unroll
                for (int r = 0; r < 4; r++)
                    Pbuf[wv][q4 * 4 + r][ct * 16 + l16] = f2b(s[ct][r]);
            f32x4 accp[2];
            accp[0] = (f32x4){0.f, 0.f, 0.f, 0.f};
            accp[1] = (f32x4){0.f, 0.f, 0.f, 0.f};
#pragma unroll
            for (int ks = 0; ks < 2; ks++) {
                bf16x8 pa = *(const bf16x8*)&Pbuf[wv][l16][ks * 32 + q4 * 8];
#pragma unroll
                for (int jt = 0; jt < 2; jt++) {
                    bf16x8 vb = *(const bf16x8*)&vtbuf[hl][jt * 16 + l16][ks * 32 + q4 * 8];
                    accp[jt] = __builtin_amdgcn_mfma_f32_16x16x32_bf16(pa, vb, accp[jt], 0, 0, 0);
                }
            }
            __syncthreads();
            float rl[4];
#pragma unroll
            for (int r = 0; r < 4; r++) rl[r] = 1.0f / lsum[r];
#pragma unroll
            for (int jt = 0; jt < 2; jt++)
#pragma unroll
                for (int r = 0; r < 4; r++)
                    Obuf[wv * 16 + q4 * 4 + r][jt * 16 + l16] = f2b(accp[jt][r] * rl[r]);
            __syncthreads();
#pragma unroll
            for (int jtl = 0; jtl < 3; jtl++) {
                int jb = (wv * 3 + jtl) * 16;
                bf16x8 pb = *(const bf16x8*)(pwt + (size_t)(jb + l16) * CDIM + h * 32 + q4 * 8);
#pragma unroll
                for (int mt = 0; mt < 4; mt++) {
                    bf16x8 oa = *(const bf16x8*)&Obuf[mt * 16 + l16][q4 * 8];
                    acco[jtl][mt] = __builtin_amdgcn_mfma_f32_16x16x32_bf16(oa, pb, acco[jtl][mt], 0, 0, 0);
                }
            }
        }
    }

#pragma unroll
    for (int jtl = 0; jtl < 3; jtl++) {
        int jb = (wv * 3 + jtl) * 16;
        float bias = projb[jb + l16];
#pragma unroll
        for (int mt = 0; mt < 4; mt++)
#pragma unroll
            for (int r = 0; r < 4; r++) {
                int n = mt * 16 + q4 * 4 + r;
                if (n < NTOK)
                    out[((size_t)b * NTOK + n) * CDIM + jb + l16] = acco[jtl][mt][r] + bias;
            }
    }
}

extern "C" void kernel_launch(void* const* d_in, const int* in_sizes, int n_in,
                              void* d_out, int out_size, void* d_ws, size_t ws_size,
                              hipStream_t stream) {
    const float* x      = (const float*)d_in[0];
    const float* mask   = (const float*)d_in[1];
    const float* qkv_w  = (const float*)d_in[2];
    const float* qkv_b  = (const float*)d_in[3];
    const float* proj_w = (const float*)d_in[4];
    const float* proj_b = (const float*)d_in[5];
    short* wt  = (short*)d_ws;                 // [576][192] bf16
    short* pwt = wt + CDIM * 3 * CDIM;         // [192][192] bf16
    float* out = (float*)d_out;
    int B = in_sizes[0] / (NTOK * CDIM);       // 4096

    transpose_w<<<(CDIM * 3 * CDIM + 255) / 256, 256, 0, stream>>>(qkv_w, proj_w, wt, pwt);

    size_t wbytes = (size_t)(CDIM * 3 * CDIM + CDIM * CDIM) * sizeof(short);
    size_t obytes = (size_t)B * 64 * CDIM * sizeof(short);
    if (ws_size >= wbytes + obytes) {
        short* obuf = pwt + CDIM * CDIM;       // [B][64][192] bf16
        attn_head_kernel<<<B * NHEADS, 256, 0, stream>>>(x, mask, wt, qkv_b, obuf);
        proj_kernel<<<B, 256, 0, stream>>>(obuf, pwt, proj_b, out);
    } else {
        winattn_kernel<<<B, 256, 0, stream>>>(x, mask, wt, qkv_b, pwt, proj_b, out);
    }
}

// Round 2
// 749.006 us; speedup vs baseline: 1.1220x; 1.1220x over previous
//
#include <hip/hip_runtime.h>
#include <hip/hip_bf16.h>
#include <stdint.h>

#define NTOK 49
#define CDIM 192
#define NHEADS 6

typedef __attribute__((ext_vector_type(8))) short bf16x8;
typedef __attribute__((ext_vector_type(4))) float f32x4;

// RNE float -> bf16 (bit trick)
__device__ __forceinline__ short f2b(float f) {
    uint32_t u = __float_as_uint(f);
    uint32_t r = (u + 0x7fffu + ((u >> 16) & 1u)) >> 16;
    return (short)r;
}

// Fast pack: 8 consecutive fp32 -> bf16x8 (round-half-up via +0x8000, then v_perm)
__device__ __forceinline__ bf16x8 cvt8(const float* p) {
    f32x4 a = *(const f32x4*)p;
    f32x4 b = *(const f32x4*)(p + 4);
    union { uint32_t u[4]; bf16x8 v; } r;
    uint32_t e0 = __float_as_uint(a[0]) + 0x8000u, e1 = __float_as_uint(a[1]) + 0x8000u;
    uint32_t e2 = __float_as_uint(a[2]) + 0x8000u, e3 = __float_as_uint(a[3]) + 0x8000u;
    uint32_t e4 = __float_as_uint(b[0]) + 0x8000u, e5 = __float_as_uint(b[1]) + 0x8000u;
    uint32_t e6 = __float_as_uint(b[2]) + 0x8000u, e7 = __float_as_uint(b[3]) + 0x8000u;
    r.u[0] = __builtin_amdgcn_perm(e1, e0, 0x07060302u);
    r.u[1] = __builtin_amdgcn_perm(e3, e2, 0x07060302u);
    r.u[2] = __builtin_amdgcn_perm(e5, e4, 0x07060302u);
    r.u[3] = __builtin_amdgcn_perm(e7, e6, 0x07060302u);
    return r.v;
}

// One-shot: transpose+cast qkv_w [192][576]f32 -> wt [576][192]bf16,
//           proj_w [192][192]f32 -> pwt [192][192]bf16
__global__ void transpose_w(const float* __restrict__ qkv_w,
                            const float* __restrict__ proj_w,
                            short* __restrict__ wt, short* __restrict__ pwt) {
    int idx = blockIdx.x * 256 + threadIdx.x;
    if (idx < CDIM * 3 * CDIM) {
        int c = idx / (3 * CDIM), j = idx % (3 * CDIM);
        wt[j * CDIM + c] = f2b(qkv_w[idx]);
    }
    if (idx < CDIM * CDIM) {
        int c = idx / CDIM, j = idx % CDIM;
        pwt[j * CDIM + c] = f2b(proj_w[idx]);
    }
}

// ===================== kernel A: QKV + attention, one block per window =====================
// 4 waves; wave wv owns token mtile wv (rows wv*16..wv*16+15) for QKV and attention.
// x read ONCE per window; 2 barriers per head-pair (6 total); O -> bf16 workspace.
// LDS 38.4 KB -> 4 blocks/CU; regs ~110 -> 4 waves/SIMD -> 16 waves/CU (50%).
__global__ __launch_bounds__(256, 4)
void winattn_qkv_attn(const float* __restrict__ x, const float* __restrict__ mask,
                      const short* __restrict__ wt, const float* __restrict__ qkvb,
                      short* __restrict__ obuf /* [B][64][CDIM] bf16 */) {
    // stride notes (bank = dword%32): qbuf/kbuf row 40 sh = 80B -> <=2-way on b128 col reads;
    // vtbuf/Pbuf row 70 sh = 140B (35 dw ≡ 3 mod 32) -> 2-way on b128 reads (was 8-way at 72).
    __shared__ __align__(16) short qbuf[2][64][40];   // 10240 B [head-in-pair][token][d]
    __shared__ __align__(16) short kbuf[2][64][40];   // 10240 B
    __shared__ __align__(16) short vtbuf[2][32][70];  //  8960 B [head-in-pair][d][token]
    __shared__ __align__(16) short Pbuf[4][16][70];   //  8960 B per-wave P rows; reused as O staging

    const int b = blockIdx.x;
    const int tid = threadIdx.x;
    const int wv = tid >> 6;
    const int lane = tid & 63;
    const int q4 = lane >> 4;
    const int l16 = lane & 15;

    // ---- x A-frags: own mtile only (24 VGPRs) ----
    const float* xg = x + (size_t)b * NTOK * CDIM;
    bf16x8 zero = {};
    const int n = wv * 16 + l16;
    const bool valid = (n < NTOK);
    const float* xr = xg + n * CDIM;
    bf16x8 afr[6];
#pragma unroll
    for (int ks = 0; ks < 6; ks++)
        afr[ks] = valid ? cvt8(xr + ks * 32 + q4 * 8) : zero;

    // ---- premask: mask value (+ -inf for pad rows/cols); rows = wv*16 + q4*4 + r ----
    const float* mg = mask + (size_t)(b & 63) * NTOK * NTOK;
    float premask[4][4];
#pragma unroll
    for (int ct = 0; ct < 4; ct++)
#pragma unroll
        for (int r = 0; r < 4; r++) {
            int row = wv * 16 + q4 * 4 + r;
            int col = ct * 16 + l16;
            float mv = mg[min(row, 48) * NTOK + min(col, 48)];
            premask[ct][r] = (row < NTOK && col < NTOK) ? mv : -1e30f;
        }

    const float SCALE = 0.17677669529663687f;

    for (int p = 0; p < 3; p++) {            // head pairs (2p, 2p+1)
        __syncthreads();                     // q/k/vt overwrite vs prior pair's reads

        // ---- QKV for pair: 12 jtiles, each wave computes its OWN mtile for all 12 ----
#pragma unroll 2
        for (int jt = 0; jt < 12; jt++) {
            int sect = jt >> 2;                        // 0=q 1=k 2=v
            int within = jt & 3;                       // 16-col tile within pair's 64 cols
            int jb = sect * CDIM + p * 64 + within * 16;
            const short* wrow = wt + (size_t)(jb + l16) * CDIM;
            bf16x8 bfr[6];
#pragma unroll
            for (int ks = 0; ks < 6; ks++)
                bfr[ks] = *(const bf16x8*)(wrow + ks * 32 + q4 * 8);
            f32x4 acc = (f32x4){0.f, 0.f, 0.f, 0.f};
#pragma unroll
            for (int ks = 0; ks < 6; ks++)
                acc = __builtin_amdgcn_mfma_f32_16x16x32_bf16(afr[ks], bfr[ks], acc, 0, 0, 0);
            float bias = qkvb[jb + l16];
            int hl = within >> 1;                      // head within pair
            int d = (within & 1) * 16 + l16;           // dim within head [0,32)
#pragma unroll
            for (int r = 0; r < 4; r++) {
                int row = wv * 16 + q4 * 4 + r;
                short v = f2b(acc[r] + bias);
                if (sect == 0)      qbuf[hl][row][d] = v;
                else if (sect == 1) kbuf[hl][row][d] = v;
                else                vtbuf[hl][d][row] = v;
            }
        }
        __syncthreads();                     // K/V rows from all waves visible

        // ---- attention per head: fully wave-private, no barriers ----
#pragma unroll
        for (int hl = 0; hl < 2; hl++) {
            // S = Q K^T (wave's 16 query rows; K=32 in one MFMA)
            f32x4 accs[4];
#pragma unroll
            for (int c = 0; c < 4; c++) accs[c] = (f32x4){0.f, 0.f, 0.f, 0.f};
            bf16x8 qa = *(const bf16x8*)&qbuf[hl][wv * 16 + l16][q4 * 8];
#pragma unroll
            for (int ct = 0; ct < 4; ct++) {
                bf16x8 kb = *(const bf16x8*)&kbuf[hl][ct * 16 + l16][q4 * 8];
                accs[ct] = __builtin_amdgcn_mfma_f32_16x16x32_bf16(qa, kb, accs[ct], 0, 0, 0);
            }
            // softmax across 64 cols: in-lane over 4 ct + 16-lane xor shuffle
            float s[4][4], mx[4], lsum[4];
#pragma unroll
            for (int r = 0; r < 4; r++) {
                mx[r] = -3.4e38f;
#pragma unroll
                for (int ct = 0; ct < 4; ct++) {
                    s[ct][r] = accs[ct][r] * SCALE + premask[ct][r];
                    mx[r] = fmaxf(mx[r], s[ct][r]);
                }
            }
#pragma unroll
            for (int w2 = 1; w2 < 16; w2 <<= 1)
#pragma unroll
                for (int r = 0; r < 4; r++) mx[r] = fmaxf(mx[r], __shfl_xor(mx[r], w2));
#pragma unroll
            for (int r = 0; r < 4; r++) lsum[r] = 0.f;
#pragma unroll
            for (int ct = 0; ct < 4; ct++)
#pragma unroll
                for (int r = 0; r < 4; r++) {
                    float e = __expf(s[ct][r] - mx[r]);
                    s[ct][r] = e;
                    lsum[r] += e;
                }
#pragma unroll
            for (int w2 = 1; w2 < 16; w2 <<= 1)
#pragma unroll
                for (int r = 0; r < 4; r++) lsum[r] += __shfl_xor(lsum[r], w2);
            // P -> wave-private LDS (C-layout -> A-layout), unnormalized
#pragma unroll
            for (int ct = 0; ct < 4; ct++)
#pragma unroll
                for (int r = 0; r < 4; r++)
                    Pbuf[wv][q4 * 4 + r][ct * 16 + l16] = f2b(s[ct][r]);
            // O = P V (wave-private)
            f32x4 accp[2];
            accp[0] = (f32x4){0.f, 0.f, 0.f, 0.f};
            accp[1] = (f32x4){0.f, 0.f, 0.f, 0.f};
#pragma unroll
            for (int ks = 0; ks < 2; ks++) {
                bf16x8 pa = *(const bf16x8*)&Pbuf[wv][l16][ks * 32 + q4 * 8];
#pragma unroll
                for (int jt2 = 0; jt2 < 2; jt2++) {
                    bf16x8 vb = *(const bf16x8*)&vtbuf[hl][jt2 * 16 + l16][ks * 32 + q4 * 8];
                    accp[jt2] = __builtin_amdgcn_mfma_f32_16x16x32_bf16(pa, vb, accp[jt2], 0, 0, 0);
                }
            }
            float rl[4];
#pragma unroll
            for (int r = 0; r < 4; r++) rl[r] = 1.0f / lsum[r];
            // normalize + stage in the (now dead) wave-private Pbuf region, coalesced store
#pragma unroll
            for (int jt2 = 0; jt2 < 2; jt2++)
#pragma unroll
                for (int r = 0; r < 4; r++)
                    Pbuf[wv][q4 * 4 + r][jt2 * 16 + l16] = f2b(accp[jt2][r] * rl[r]);
            bf16x8 ox = *(const bf16x8*)&Pbuf[wv][l16][q4 * 8];
            short* op = obuf + ((size_t)(b * 64 + wv * 16 + l16)) * CDIM + (2 * p + hl) * 32 + q4 * 8;
            *(bf16x8*)op = ox;
        }
    }
}

// ===================== kernel B: proj GEMM [B*64,192] x [192,192] + bias -> fp32 =====================
__global__ __launch_bounds__(256, 4)
void proj_kernel(const short* __restrict__ obuf, const short* __restrict__ pwt,
                 const float* __restrict__ projb, float* __restrict__ out) {
    const int b = blockIdx.x;
    const int tid = threadIdx.x;
    const int wv = tid >> 6;
    const int lane = tid & 63;
    const int q4 = lane >> 4;
    const int l16 = lane & 15;
    const short* og = obuf + (size_t)b * 64 * CDIM;

#pragma unroll
    for (int mp = 0; mp < 2; mp++) {
        bf16x8 afr[2][6];
#pragma unroll
        for (int mt = 0; mt < 2; mt++) {
            int row = mp * 32 + mt * 16 + l16;
#pragma unroll
            for (int ks = 0; ks < 6; ks++)
                afr[mt][ks] = *(const bf16x8*)(og + (size_t)row * CDIM + ks * 32 + q4 * 8);
        }
#pragma unroll
        for (int jtl = 0; jtl < 3; jtl++) {
            int jb = (wv * 3 + jtl) * 16;
            const short* wrow = pwt + (size_t)(jb + l16) * CDIM;
            bf16x8 bfr[6];
#pragma unroll
            for (int ks = 0; ks < 6; ks++)
                bfr[ks] = *(const bf16x8*)(wrow + ks * 32 + q4 * 8);
            float bias = projb[jb + l16];
#pragma unroll
            for (int mt = 0; mt < 2; mt++) {
                f32x4 acc = (f32x4){0.f, 0.f, 0.f, 0.f};
#pragma unroll
                for (int ks = 0; ks < 6; ks++)
                    acc = __builtin_amdgcn_mfma_f32_16x16x32_bf16(afr[mt][ks], bfr[ks], acc, 0, 0, 0);
#pragma unroll
                for (int r = 0; r < 4; r++) {
                    int nrow = mp * 32 + mt * 16 + q4 * 4 + r;
                    if (nrow < NTOK)
                        out[((size_t)b * NTOK + nrow) * CDIM + jb + l16] = acc[r] + bias;
                }
            }
        }
    }
}

// ===================== fallback fused path (verified baseline, used only if ws too small) =====================
__global__ __launch_bounds__(256, 1)
void winattn_kernel(const float* __restrict__ x, const float* __restrict__ mask,
                    const short* __restrict__ wt, const float* __restrict__ qkvb,
                    const short* __restrict__ pwt, const float* __restrict__ projb,
                    float* __restrict__ out) {
    __shared__ __align__(16) short qbuf[2][64][40];
    __shared__ __align__(16) short kbuf[2][64][40];
    __shared__ __align__(16) short vtbuf[2][32][72];
    __shared__ __align__(16) short Pbuf[4][16][72];
    __shared__ __align__(16) short Obuf[64][40];

    const int b = blockIdx.x;
    const int tid = threadIdx.x;
    const int wv = tid >> 6;
    const int lane = tid & 63;
    const int q4 = lane >> 4;
    const int l16 = lane & 15;

    const float* xg = x + (size_t)b * NTOK * CDIM;
    bf16x8 zero = {};
    bf16x8 afr[4][6];
#pragma unroll
    for (int mt = 0; mt < 4; mt++) {
        int n = mt * 16 + l16;
        const float* xr = xg + n * CDIM;
        bool valid = (n < NTOK);
#pragma unroll
        for (int ks = 0; ks < 6; ks++)
            afr[mt][ks] = valid ? cvt8(xr + ks * 32 + q4 * 8) : zero;
    }

    const float* mg = mask + (size_t)(b & 63) * NTOK * NTOK;
    float premask[4][4];
#pragma unroll
    for (int ct = 0; ct < 4; ct++)
#pragma unroll
        for (int r = 0; r < 4; r++) {
            int row = wv * 16 + q4 * 4 + r;
            int col = ct * 16 + l16;
            float mv = mg[min(row, 48) * NTOK + min(col, 48)];
            premask[ct][r] = (row < NTOK && col < NTOK) ? mv : -1e30f;
        }

    f32x4 acco[3][4];
#pragma unroll
    for (int a = 0; a < 3; a++)
#pragma unroll
        for (int m = 0; m < 4; m++) acco[a][m] = (f32x4){0.f, 0.f, 0.f, 0.f};

    const float SCALE = 0.17677669529663687f;

    for (int p = 0; p < 3; p++) {
        __syncthreads();
#pragma unroll
        for (int t = 0; t < 3; t++) {
            int i = wv * 3 + t;
            int jt;
            if (i < 4)      jt = 4 * p + i;
            else if (i < 8) jt = 12 + 4 * p + (i - 4);
            else            jt = 24 + 4 * p + (i - 8);
            int jb = jt * 16;
            const short* wrow = wt + (size_t)(jb + l16) * CDIM;
            bf16x8 bfr[6];
#pragma unroll
            for (int ks = 0; ks < 6; ks++)
                bfr[ks] = *(const bf16x8*)(wrow + ks * 32 + q4 * 8);
            f32x4 acc[4];
#pragma unroll
            for (int m = 0; m < 4; m++) acc[m] = (f32x4){0.f, 0.f, 0.f, 0.f};
#pragma unroll
            for (int ks = 0; ks < 6; ks++)
#pragma unroll
                for (int mt = 0; mt < 4; mt++)
                    acc[mt] = __builtin_amdgcn_mfma_f32_16x16x32_bf16(afr[mt][ks], bfr[ks], acc[mt], 0, 0, 0);
            float bias = qkvb[jb + l16];
            int sect = jb / CDIM;
            int jm = jb % CDIM;
            int hl = (jm / 32) - 2 * p;
            int d = (jm % 32) + l16;
#pragma unroll
            for (int mt = 0; mt < 4; mt++)
#pragma unroll
                for (int r = 0; r < 4; r++) {
                    int row = mt * 16 + q4 * 4 + r;
                    short v = f2b(acc[mt][r] + bias);
                    if (sect == 0)      qbuf[hl][row][d] = v;
                    else if (sect == 1) kbuf[hl][row][d] = v;
                    else                vtbuf[hl][d][row] = v;
                }
        }
        __syncthreads();

#pragma unroll
        for (int hl = 0; hl < 2; hl++) {
            int h = 2 * p + hl;
            f32x4 accs[4];
#pragma unroll
            for (int c = 0; c < 4; c++) accs[c] = (f32x4){0.f, 0.f, 0.f, 0.f};
            bf16x8 qa = *(const bf16x8*)&qbuf[hl][wv * 16 + l16][q4 * 8];
#pragma unroll
            for (int ct = 0; ct < 4; ct++) {
                bf16x8 kb = *(const bf16x8*)&kbuf[hl][ct * 16 + l16][q4 * 8];
                accs[ct] = __builtin_amdgcn_mfma_f32_16x16x32_bf16(qa, kb, accs[ct], 0, 0, 0);
            }
            float s[4][4], mx[4], lsum[4];
#pragma unroll
            for (int r = 0; r < 4; r++) {
                mx[r] = -3.4e38f;
#pragma unroll
                for (int ct = 0; ct < 4; ct++) {
                    s[ct][r] = accs[ct][r] * SCALE + premask[ct][r];
                    mx[r] = fmaxf(mx[r], s[ct][r]);
                }
            }
#pragma unroll
            for (int w2 = 1; w2 < 16; w2 <<= 1)
#pragma unroll
                for (int r = 0; r < 4; r++) mx[r] = fmaxf(mx[r], __shfl_xor(mx[r], w2));
#pragma unroll
            for (int r = 0; r < 4; r++) lsum[r] = 0.f;
#pragma unroll
            for (int ct = 0; ct < 4; ct++)
#pragma unroll
                for (int r = 0; r < 4; r++) {
                    float e = __expf(s[ct][r] - mx[r]);
                    s[ct][r] = e;
                    lsum[r] += e;
                }
#pragma unroll
            for (int w2 = 1; w2 < 16; w2 <<= 1)
#pragma unroll
                for (int r = 0; r < 4; r++) lsum[r] += __shfl_xor(lsum[r], w2);
#pragma unroll
            for (int ct = 0; ct < 4; ct++)
#pragma unroll
                for (int r = 0; r < 4; r++)
                    Pbuf[wv][q4 * 4 + r][ct * 16 + l16] = f2b(s[ct][r]);
            f32x4 accp[2];
            accp[0] = (f32x4){0.f, 0.f, 0.f, 0.f};
            accp[1] = (f32x4){0.f, 0.f, 0.f, 0.f};
#pragma unroll
            for (int ks = 0; ks < 2; ks++) {
                bf16x8 pa = *(const bf16x8*)&Pbuf[wv][l16][ks * 32 + q4 * 8];
#pragma unroll
                for (int jt = 0; jt < 2; jt++) {
                    bf16x8 vb = *(const bf16x8*)&vtbuf[hl][jt * 16 + l16][ks * 32 + q4 * 8];
                    accp[jt] = __builtin_amdgcn_mfma_f32_16x16x32_bf16(pa, vb, accp[jt], 0, 0, 0);
                }
            }
            __syncthreads();
            float rl[4];
#pragma unroll
            for (int r = 0; r < 4; r++) rl[r] = 1.0f / lsum[r];
#pragma unroll
            for (int jt = 0; jt < 2; jt++)
#pragma unroll
                for (int r = 0; r < 4; r++)
                    Obuf[wv * 16 + q4 * 4 + r][jt * 16 + l16] = f2b(accp[jt][r] * rl[r]);
            __syncthreads();
#pragma unroll
            for (int jtl = 0; jtl < 3; jtl++) {
                int jb = (wv * 3 + jtl) * 16;
                bf16x8 pb = *(const bf16x8*)(pwt + (size_t)(jb + l16) * CDIM + h * 32 + q4 * 8);
#pragma unroll
                for (int mt = 0; mt < 4; mt++) {
                    bf16x8 oa = *(const bf16x8*)&Obuf[mt * 16 + l16][q4 * 8];
                    acco[jtl][mt] = __builtin_amdgcn_mfma_f32_16x16x32_bf16(oa, pb, acco[jtl][mt], 0, 0, 0);
                }
            }
        }
    }

#pragma unroll
    for (int jtl = 0; jtl < 3; jtl++) {
        int jb = (wv * 3 + jtl) * 16;
        float bias = projb[jb + l16];
#pragma unroll
        for (int mt = 0; mt < 4; mt++)
#pragma unroll
            for (int r = 0; r < 4; r++) {
                int n = mt * 16 + q4 * 4 + r;
                if (n < NTOK)
                    out[((size_t)b * NTOK + n) * CDIM + jb + l16] = acco[jtl][mt][r] + bias;
            }
    }
}

extern "C" void kernel_launch(void* const* d_in, const int* in_sizes, int n_in,
                              void* d_out, int out_size, void* d_ws, size_t ws_size,
                              hipStream_t stream) {
    const float* x      = (const float*)d_in[0];
    const float* mask   = (const float*)d_in[1];
    const float* qkv_w  = (const float*)d_in[2];
    const float* qkv_b  = (const float*)d_in[3];
    const float* proj_w = (const float*)d_in[4];
    const float* proj_b = (const float*)d_in[5];
    short* wt  = (short*)d_ws;                 // [576][192] bf16
    short* pwt = wt + CDIM * 3 * CDIM;         // [192][192] bf16
    float* out = (float*)d_out;
    int B = in_sizes[0] / (NTOK * CDIM);       // 4096

    transpose_w<<<(CDIM * 3 * CDIM + 255) / 256, 256, 0, stream>>>(qkv_w, proj_w, wt, pwt);

    size_t wbytes = (size_t)(CDIM * 3 * CDIM + CDIM * CDIM) * sizeof(short);
    size_t obytes = (size_t)B * 64 * CDIM * sizeof(short);
    if (ws_size >= wbytes + obytes) {
        short* obuf = pwt + CDIM * CDIM;       // [B][64][192] bf16
        winattn_qkv_attn<<<B, 256, 0, stream>>>(x, mask, wt, qkv_b, obuf);
        proj_kernel<<<B, 256, 0, stream>>>(obuf, pwt, proj_b, out);
    } else {
        winattn_kernel<<<B, 256, 0, stream>>>(x, mask, wt, qkv_b, pwt, proj_b, out);
    }
}